// Round 1
// baseline (191.829 us; speedup 1.0000x reference)
//
#include <hip/hip_runtime.h>

#define DD 96
#define HH 128
#define WW 160
#define NN (DD * HH * WW)

__global__ __launch_bounds__(256) void warp3d_kernel(
    const float* __restrict__ src,    // (D,H,W,2)
    const float* __restrict__ flow,   // (N,7): t0 t1 t2 qv0 qv1 qv2 qw
    float* __restrict__ out)          // warped(2N) | new_loc(3N) | grid(3N)
{
    int n = blockIdx.x * blockDim.x + threadIdx.x;
    if (n >= NN) return;

    int w  = n % WW;
    int hd = n / WW;
    int h  = hd % HH;
    int d  = hd / HH;

    const float inv_mx = 1.0f / 159.0f;
    float p0 = (float)(2 * d - (DD - 1)) * inv_mx;
    float p1 = (float)(2 * h - (HH - 1)) * inv_mx;
    float p2 = (float)(2 * w - (WW - 1)) * inv_mx;

    const float* f = flow + (size_t)n * 7;
    float t0 = f[0], t1 = f[1], t2 = f[2];
    float q0 = f[3], q1 = f[4], q2 = f[5], qw = f[6];

    // uv = cross(qv, p) + qw * p
    float u0 = q1 * p2 - q2 * p1 + qw * p0;
    float u1 = q2 * p0 - q0 * p2 + qw * p1;
    float u2 = q0 * p1 - q1 * p0 + qw * p2;
    // nl = p + 2 * cross(qv, uv) + t
    float nl0 = p0 + 2.0f * (q1 * u2 - q2 * u1) + t0;
    float nl1 = p1 + 2.0f * (q2 * u0 - q0 * u2) + t1;
    float nl2 = p2 + 2.0f * (q0 * u1 - q1 * u0) + t2;

    // sample coords (scale factors folded; coords reversed so x<-nl2, y<-nl1, z<-nl0)
    float ix = fminf(fmaxf(nl2 * 79.5f + 79.5f, 0.0f), (float)(WW - 1));
    float iy = fminf(fmaxf(nl1 * 79.5f + 63.5f, 0.0f), (float)(HH - 1));
    float iz = fminf(fmaxf(nl0 * 79.5f + 47.5f, 0.0f), (float)(DD - 1));

    int x0 = (int)floorf(ix); int x1 = min(x0 + 1, WW - 1);
    int y0 = (int)floorf(iy); int y1 = min(y0 + 1, HH - 1);
    int z0 = (int)floorf(iz); int z1 = min(z0 + 1, DD - 1);
    float wx = ix - (float)x0;
    float wy = iy - (float)y0;
    float wz = iz - (float)z0;

    const float2* v = (const float2*)src;  // channels adjacent in memory
    int b00 = (z0 * HH + y0) * WW;
    int b01 = (z0 * HH + y1) * WW;
    int b10 = (z1 * HH + y0) * WW;
    int b11 = (z1 * HH + y1) * WW;

    float2 c000 = v[b00 + x0];
    float2 c001 = v[b00 + x1];
    float2 c010 = v[b01 + x0];
    float2 c011 = v[b01 + x1];
    float2 c100 = v[b10 + x0];
    float2 c101 = v[b10 + x1];
    float2 c110 = v[b11 + x0];
    float2 c111 = v[b11 + x1];

    float wx1 = 1.0f - wx, wy1 = 1.0f - wy, wz1 = 1.0f - wz;
    float w000 = wz1 * wy1 * wx1;
    float w001 = wz1 * wy1 * wx;
    float w010 = wz1 * wy  * wx1;
    float w011 = wz1 * wy  * wx;
    float w100 = wz  * wy1 * wx1;
    float w101 = wz  * wy1 * wx;
    float w110 = wz  * wy  * wx1;
    float w111 = wz  * wy  * wx;

    float o0 = c000.x * w000 + c001.x * w001 + c010.x * w010 + c011.x * w011
             + c100.x * w100 + c101.x * w101 + c110.x * w110 + c111.x * w111;
    float o1 = c000.y * w000 + c001.y * w001 + c010.y * w010 + c011.y * w011
             + c100.y * w100 + c101.y * w101 + c110.y * w110 + c111.y * w111;

    out[n]          = o0;
    out[NN + n]     = o1;
    out[2 * NN + n] = nl0;
    out[3 * NN + n] = nl1;
    out[4 * NN + n] = nl2;
    out[5 * NN + n] = p0;
    out[6 * NN + n] = p1;
    out[7 * NN + n] = p2;
}

extern "C" void kernel_launch(void* const* d_in, const int* in_sizes, int n_in,
                              void* d_out, int out_size, void* d_ws, size_t ws_size,
                              hipStream_t stream) {
    const float* src  = (const float*)d_in[0];
    const float* flow = (const float*)d_in[1];
    float* out = (float*)d_out;
    dim3 block(256);
    dim3 grid((NN + 255) / 256);
    warp3d_kernel<<<grid, block, 0, stream>>>(src, flow, out);
}